// Round 1
// baseline (1073.092 us; speedup 1.0000x reference)
//
#include <hip/hip_runtime.h>
#include <stdint.h>

typedef __bf16 bf16;
typedef bf16 bf16x8 __attribute__((ext_vector_type(8)));
typedef bf16 bf16x4 __attribute__((ext_vector_type(4)));
typedef float f32x4 __attribute__((ext_vector_type(4)));

#define DIM   1024
#define TMAX  16
#define NTPL  64
#define BATCH 2048
#define SLEN  77

__device__ __forceinline__ void gl_lds16(const void* g, void* l) {
  __builtin_amdgcn_global_load_lds(
      (const __attribute__((address_space(1))) void*)g,
      (__attribute__((address_space(3))) void*)l, 16, 0, 0);
}

// ---------------- bucket by time_step (1 block) ----------------
__global__ void bucket_k(const int* __restrict__ ts, int* __restrict__ perm,
                         int* __restrict__ bstart) {
  __shared__ int cnt[TMAX], base[TMAX], cur[TMAX];
  int tid = threadIdx.x;
  if (tid < TMAX) { cnt[tid] = 0; cur[tid] = 0; }
  __syncthreads();
  for (int b = tid; b < BATCH; b += 256) atomicAdd(&cnt[ts[b]], 1);
  __syncthreads();
  if (tid == 0) {
    int a = 0;
    for (int t = 0; t < TMAX; ++t) { base[t] = a; bstart[t] = a; a += cnt[t]; }
    bstart[TMAX] = a;
  }
  __syncthreads();
  for (int b = tid; b < BATCH; b += 256) {
    int t = ts[b];
    perm[base[t] + atomicAdd(&cur[t], 1)] = b;
  }
}

// ---------------- fp32 -> bf16 conversions ----------------
__global__ void cvt_bf16_k(const float* __restrict__ src, bf16* __restrict__ dst) {
  int idx = blockIdx.x * 256 + threadIdx.x;
  float4 v = ((const float4*)src)[idx];
  bf16x4 o = {(bf16)v.x, (bf16)v.y, (bf16)v.z, (bf16)v.w};
  ((bf16x4*)dst)[idx] = o;
}

// textual_query -> upper half of xcat rows (row stride 2*DIM)
__global__ void cvt_tq_k(const float* __restrict__ tq, bf16* __restrict__ xcat) {
  int idx = blockIdx.x * 256 + threadIdx.x;  // BATCH*DIM/4 total
  int b = idx >> 8, c4 = idx & 255;
  float4 v = ((const float4*)(tq + (size_t)b * DIM))[c4];
  bf16x4 o = {(bf16)v.x, (bf16)v.y, (bf16)v.z, (bf16)v.w};
  *(bf16x4*)(xcat + (size_t)b * 2 * DIM + DIM + c4 * 4) = o;
}

// ---------------- generic bf16 B^T GEMM: C[M,N] = A[M,K] * B[N,K]^T + bias ----------------
// 128x128 tile, BK=32, 4 waves in 2x2, 4x4 16x16 subtiles per wave.
__global__ __launch_bounds__(256, 2) void gemm_bt(
    const bf16* __restrict__ A, int lda, const bf16* __restrict__ B, int ldb,
    const float* __restrict__ bias, bf16* __restrict__ C, int ldc,
    float* __restrict__ Cf, int N, int K, int relu) {
  __shared__ bf16 As[128 * 32];
  __shared__ bf16 Bs[128 * 32];
  const int tid = threadIdx.x;
  const int rowBase = blockIdx.y * 128, colBase = blockIdx.x * 128;

  const bf16* ag[2]; const bf16* bg[2];
  bf16* al[2]; bf16* bl[2];
#pragma unroll
  for (int i = 0; i < 2; ++i) {
    int j = tid + i * 256;
    int r = j >> 2, kq = j & 3;
    ag[i] = A + (size_t)(rowBase + r) * lda + kq * 8;
    int bn = colBase + r; if (bn > N - 1) bn = N - 1;  // clamp (N=64 case), results discarded
    bg[i] = B + (size_t)bn * ldb + kq * 8;
    al[i] = As + j * 8;
    bl[i] = Bs + j * 8;
  }
  const int wave = tid >> 6, lane = tid & 63;
  const int wm = wave >> 1, wn = wave & 1;
  const int mr = lane & 15, quad = lane >> 4;

  f32x4 acc[4][4];
#pragma unroll
  for (int i = 0; i < 4; ++i)
#pragma unroll
    for (int j = 0; j < 4; ++j) acc[i][j] = (f32x4){0.f, 0.f, 0.f, 0.f};

  for (int k0 = 0; k0 < K; k0 += 32) {
    __syncthreads();
#pragma unroll
    for (int i = 0; i < 2; ++i) {
      gl_lds16(ag[i] + k0, al[i]);
      gl_lds16(bg[i] + k0, bl[i]);
    }
    __syncthreads();
    bf16x8 af[4], bfr[4];
#pragma unroll
    for (int i = 0; i < 4; ++i)
      af[i] = *(const bf16x8*)&As[(wm * 64 + i * 16 + mr) * 32 + quad * 8];
#pragma unroll
    for (int j = 0; j < 4; ++j)
      bfr[j] = *(const bf16x8*)&Bs[(wn * 64 + j * 16 + mr) * 32 + quad * 8];
#pragma unroll
    for (int i = 0; i < 4; ++i)
#pragma unroll
      for (int j = 0; j < 4; ++j)
        acc[i][j] = __builtin_amdgcn_mfma_f32_16x16x32_bf16(af[i], bfr[j], acc[i][j], 0, 0, 0);
  }

  const int r0 = quad * 4;
#pragma unroll
  for (int i = 0; i < 4; ++i) {
    int gm = rowBase + wm * 64 + i * 16 + r0;
#pragma unroll
    for (int j = 0; j < 4; ++j) {
      int gn = colBase + wn * 64 + j * 16 + mr;
      if (gn < N) {
        float bv = bias ? bias[gn] : 0.f;
#pragma unroll
        for (int r = 0; r < 4; ++r) {
          float v = acc[i][j][r] + bv;
          if (relu) v = fmaxf(v, 0.f);
          C[(size_t)(gm + r) * ldc + gn] = (bf16)v;
          if (Cf) Cf[(size_t)(gm + r) * ldc + gn] = v;
        }
      }
    }
  }
}

// ---------------- stage 1: per-t gathered GEMM  x1[perm] = ts[perm] @ W1[t]^T + W1_b[t] ----------------
__global__ __launch_bounds__(256, 2) void gemm_stage1(
    const bf16* __restrict__ tsbf, const bf16* __restrict__ W1bf,
    const float* __restrict__ W1b, const int* __restrict__ perm,
    const int* __restrict__ bstart, bf16* __restrict__ xcat) {
  const int t = blockIdx.z;
  const int s0 = bstart[t];
  const int cnt = bstart[t + 1] - s0;
  const int by = blockIdx.y;
  if (by * 128 >= cnt) return;
  __shared__ bf16 As[128 * 32];
  __shared__ bf16 Bs[128 * 32];
  const int tid = threadIdx.x;
  const int colBase = blockIdx.x * 128;
  const bf16* Bmat = W1bf + ((size_t)t << 20);

  const bf16* ag[2]; const bf16* bg[2];
  bf16* al[2]; bf16* bl[2];
#pragma unroll
  for (int i = 0; i < 2; ++i) {
    int j = tid + i * 256;
    int r = j >> 2, kq = j & 3;
    int lr = by * 128 + r;
    int src = perm[s0 + (lr < cnt ? lr : 0)];
    ag[i] = tsbf + (size_t)src * DIM + kq * 8;
    bg[i] = Bmat + (size_t)(colBase + r) * DIM + kq * 8;
    al[i] = As + j * 8;
    bl[i] = Bs + j * 8;
  }
  const int wave = tid >> 6, lane = tid & 63;
  const int wm = wave >> 1, wn = wave & 1;
  const int mr = lane & 15, quad = lane >> 4;

  f32x4 acc[4][4];
#pragma unroll
  for (int i = 0; i < 4; ++i)
#pragma unroll
    for (int j = 0; j < 4; ++j) acc[i][j] = (f32x4){0.f, 0.f, 0.f, 0.f};

  for (int k0 = 0; k0 < DIM; k0 += 32) {
    __syncthreads();
#pragma unroll
    for (int i = 0; i < 2; ++i) {
      gl_lds16(ag[i] + k0, al[i]);
      gl_lds16(bg[i] + k0, bl[i]);
    }
    __syncthreads();
    bf16x8 af[4], bfr[4];
#pragma unroll
    for (int i = 0; i < 4; ++i)
      af[i] = *(const bf16x8*)&As[(wm * 64 + i * 16 + mr) * 32 + quad * 8];
#pragma unroll
    for (int j = 0; j < 4; ++j)
      bfr[j] = *(const bf16x8*)&Bs[(wn * 64 + j * 16 + mr) * 32 + quad * 8];
#pragma unroll
    for (int i = 0; i < 4; ++i)
#pragma unroll
      for (int j = 0; j < 4; ++j)
        acc[i][j] = __builtin_amdgcn_mfma_f32_16x16x32_bf16(af[i], bfr[j], acc[i][j], 0, 0, 0);
  }

  const int r0 = quad * 4;
#pragma unroll
  for (int i = 0; i < 4; ++i) {
    int lr = by * 128 + wm * 64 + i * 16 + r0;
#pragma unroll
    for (int j = 0; j < 4; ++j) {
      int gn = colBase + wn * 64 + j * 16 + mr;
      float bv = W1b[t * DIM + gn];
#pragma unroll
      for (int r = 0; r < 4; ++r) {
        if (lr + r < cnt) {
          int bidx = perm[s0 + lr + r];
          xcat[(size_t)bidx * 2 * DIM + gn] = (bf16)(acc[i][j][r] + bv);
        }
      }
    }
  }
}

// ---------------- softmax over 64 templates (1 wave per row) ----------------
__global__ __launch_bounds__(256) void softmax64_k(const bf16* __restrict__ logits,
                                                   float* __restrict__ out) {
  int row = blockIdx.x * 4 + (threadIdx.x >> 6);
  int lane = threadIdx.x & 63;
  float v = (float)logits[row * NTPL + lane];
  float mx = v;
#pragma unroll
  for (int o = 32; o; o >>= 1) mx = fmaxf(mx, __shfl_xor(mx, o));
  float e = __expf(v - mx);
  float s = e;
#pragma unroll
  for (int o = 32; o; o >>= 1) s += __shfl_xor(s, o);
  out[row * NTPL + lane] = e / s;
}

// ---------------- fused word attention: scores + softmax + c_t (online softmax, 1 pass) ----------------
__global__ __launch_bounds__(256) void attn_k(
    const float* __restrict__ x, const float* __restrict__ attn_w,
    const float* __restrict__ attn_b, const float* __restrict__ feats,
    float* __restrict__ words, float* __restrict__ ct) {
  const int b = blockIdx.x;
  const int tid = threadIdx.x;
  const float* fb = feats + (size_t)b * SLEN * DIM;
  float4 aw = ((const float4*)attn_w)[tid];
  float4 xv = ((const float4*)(x + (size_t)b * DIM))[tid];
  const float v0 = xv.x * aw.x, v1 = xv.y * aw.y, v2 = xv.z * aw.z, v3 = xv.w * aw.w;
  const float ab = attn_b[0];
  __shared__ float red[4];
  __shared__ float sc[SLEN];
  const int wave = tid >> 6, lane = tid & 63;
  float m = -1e30f, l = 0.f;
  float a0 = 0.f, a1 = 0.f, a2 = 0.f, a3 = 0.f;
  float4 f = ((const float4*)fb)[tid];
  for (int s = 0; s < SLEN; ++s) {
    float4 fn = make_float4(0.f, 0.f, 0.f, 0.f);
    if (s + 1 < SLEN) fn = ((const float4*)(fb + (size_t)(s + 1) * DIM))[tid];  // prefetch
    float p = f.x * v0 + f.y * v1 + f.z * v2 + f.w * v3;
#pragma unroll
    for (int o = 32; o; o >>= 1) p += __shfl_down(p, o);
    if (lane == 0) red[wave] = p;
    __syncthreads();
    float score = red[0] + red[1] + red[2] + red[3] + ab;
    __syncthreads();
    if (tid == 0) sc[s] = score;
    float mn = fmaxf(m, score);
    float scale = __expf(m - mn);
    float w = __expf(score - mn);
    l = l * scale + w;
    a0 = a0 * scale + w * f.x;
    a1 = a1 * scale + w * f.y;
    a2 = a2 * scale + w * f.z;
    a3 = a3 * scale + w * f.w;
    m = mn;
    f = fn;
  }
  __syncthreads();
  float inv = 1.f / l;
  if (tid < SLEN) words[(size_t)b * SLEN + tid] = __expf(sc[tid] - m) * inv;
  float4 o; o.x = a0 * inv; o.y = a1 * inv; o.z = a2 * inv; o.w = a3 * inv;
  ((float4*)(ct + (size_t)b * DIM))[tid] = o;
}

extern "C" void kernel_launch(void* const* d_in, const int* in_sizes, int n_in,
                              void* d_out, int out_size, void* d_ws, size_t ws_size,
                              hipStream_t stream) {
  const float* feats = (const float*)d_in[0];
  const float* tsent = (const float*)d_in[1];
  const float* tq    = (const float*)d_in[2];
  const int*   tstep = (const int*)d_in[3];
  const float* W1w = (const float*)d_in[4];
  const float* W1b = (const float*)d_in[5];
  const float* W2w = (const float*)d_in[6];
  const float* W2b = (const float*)d_in[7];
  const float* m1w = (const float*)d_in[8];
  const float* m1b = (const float*)d_in[9];
  const float* m2w = (const float*)d_in[10];
  const float* m2b = (const float*)d_in[11];
  const float* m3w = (const float*)d_in[12];
  const float* m3b = (const float*)d_in[13];
  const float* attw = (const float*)d_in[14];
  const float* attb = (const float*)d_in[15];

  char* p = (char*)d_ws;
  auto alloc = [&](size_t bytes) { char* q = p; p += (bytes + 255) & ~(size_t)255; return q; };
  int*  perm   = (int*)alloc(BATCH * 4);
  int*  bstart = (int*)alloc(17 * 4);
  bf16* tsbf = (bf16*)alloc((size_t)BATCH * DIM * 2);
  bf16* W1bf = (bf16*)alloc((size_t)TMAX * DIM * DIM * 2);
  bf16* W2bf = (bf16*)alloc((size_t)DIM * 2 * DIM * 2);
  bf16* m1bf = (bf16*)alloc((size_t)DIM * DIM * 2);
  bf16* m2bf = (bf16*)alloc((size_t)DIM * DIM * 2);
  bf16* m3bf = (bf16*)alloc((size_t)NTPL * DIM * 2);
  bf16* xcat = (bf16*)alloc((size_t)BATCH * 2 * DIM * 2);  // [x1 | tq] bf16, lda=2048
  bf16* xbf  = (bf16*)alloc((size_t)BATCH * DIM * 2);
  float* xf  = (float*)alloc((size_t)BATCH * DIM * 4);     // fp32 x for attention
  bf16* h1   = (bf16*)alloc((size_t)BATCH * DIM * 2);
  bf16* h2   = (bf16*)alloc((size_t)BATCH * DIM * 2);
  bf16* lg   = (bf16*)alloc((size_t)BATCH * NTPL * 2);

  float* out_td = (float*)d_out;
  float* out_w  = out_td + (size_t)BATCH * NTPL;
  float* out_ct = out_w + (size_t)BATCH * SLEN;

  bucket_k<<<1, 256, 0, stream>>>(tstep, perm, bstart);
  cvt_bf16_k<<<(TMAX * DIM * DIM) / 1024, 256, 0, stream>>>(W1w, W1bf);
  cvt_bf16_k<<<(BATCH * DIM) / 1024, 256, 0, stream>>>(tsent, tsbf);
  cvt_bf16_k<<<(DIM * 2 * DIM) / 1024, 256, 0, stream>>>(W2w, W2bf);
  cvt_bf16_k<<<(DIM * DIM) / 1024, 256, 0, stream>>>(m1w, m1bf);
  cvt_bf16_k<<<(DIM * DIM) / 1024, 256, 0, stream>>>(m2w, m2bf);
  cvt_bf16_k<<<(NTPL * DIM) / 1024, 256, 0, stream>>>(m3w, m3bf);
  cvt_tq_k<<<(BATCH * DIM) / 1024, 256, 0, stream>>>(tq, xcat);

  // x1 (gathered, per-t) -> xcat[:, 0:DIM]
  gemm_stage1<<<dim3(DIM / 128, BATCH / 128, TMAX), 256, 0, stream>>>(
      tsbf, W1bf, W1b, perm, bstart, xcat);
  // x = xcat @ W2^T + b   (K=2048), also keep fp32 copy for attention
  gemm_bt<<<dim3(DIM / 128, BATCH / 128), 256, 0, stream>>>(
      xcat, 2 * DIM, W2bf, 2 * DIM, W2b, xbf, DIM, xf, DIM, 2 * DIM, 0);
  // h1 = relu(x @ m1^T + b)
  gemm_bt<<<dim3(DIM / 128, BATCH / 128), 256, 0, stream>>>(
      xbf, DIM, m1bf, DIM, m1b, h1, DIM, nullptr, DIM, DIM, 1);
  // h2 = relu(h1 @ m2^T + b)
  gemm_bt<<<dim3(DIM / 128, BATCH / 128), 256, 0, stream>>>(
      h1, DIM, m2bf, DIM, m2b, h2, DIM, nullptr, DIM, DIM, 1);
  // logits = h2 @ m3^T + b  (N=64)
  gemm_bt<<<dim3(1, BATCH / 128), 256, 0, stream>>>(
      h2, DIM, m3bf, DIM, m3b, lg, NTPL, nullptr, NTPL, DIM, 0);
  softmax64_k<<<BATCH / 4, 256, 0, stream>>>(lg, out_td);
  attn_k<<<BATCH, 256, 0, stream>>>(xf, attw, attb, feats, out_w, out_ct);
}